// Round 7
// baseline (23.993 us; speedup 1.0000x reference)
//
#include <hip/hip_runtime.h>
#include <math.h>

#define HWp 65536   // 256*256

typedef float v2f __attribute__((ext_vector_type(2)));

__device__ __forceinline__ v2f fma2(v2f a, v2f b, v2f c) {
    return __builtin_elementwise_fma(a, b, c);   // -> v_pk_fma_f32
}

__global__ __launch_bounds__(128, 6)   // force >=6 waves/SIMD (VGPR cap ~84)
void gp_encoder_kernel(const float* __restrict__ x,
                       const float* __restrict__ Wt,
                       const float* __restrict__ be,
                       float* __restrict__ out)
{
    // exchange buffers: [entry][lane], stride-1 per entry -> conflict-free
    __shared__ float Dsh[6][64];    // d6 from wave B  (written pre-bar1, read by A post-bar1)
    __shared__ float Ssh[18][64];   // S rows 3..5 (cols 0..5) from wave A (pre-bar2 -> B post-bar2)

    const int lane = threadIdx.x & 63;
    const int wid  = threadIdx.x >> 6;      // 0 = wave A (R + S), 1 = wave B (conv/m/xf/d + f64 tail)

    // block-uniform coordinates (blocks are 64-aligned within one image row)
    const int blk  = blockIdx.x;
    const int b    = blk >> 10;
    const int pixb = (blk & 1023) << 6;
    const int h    = pixb >> 8;
    const int w0   = pixb & 255;

    const bool wlo_ok = !(w0 == 0   && lane == 0);
    const bool whi_ok = !(w0 == 192 && lane == 63);
    const int  idx_m1 = wlo_ok ? lane - 1 : lane;
    const int  idx_p1 = whi_ok ? lane + 1 : lane;

    // ---------------- 3x3x3 neighborhood ----------------
    float xs[27];
    const float* xb = x + b * 3 * HWp;
    #pragma unroll
    for (int ci = 0; ci < 3; ++ci) {
        #pragma unroll
        for (int kh = 0; kh < 3; ++kh) {
            const int hh = h + kh - 1;      // scalar
            float v0 = 0.f, v1 = 0.f, v2 = 0.f;
            if ((unsigned)hh < 256u) {      // uniform branch
                const float* rp = xb + ci * HWp + hh * 256 + w0;
                v0 = rp[idx_m1];
                v1 = rp[lane];
                v2 = rp[idx_p1];
                v0 = wlo_ok ? v0 : 0.f;
                v2 = whi_ok ? v2 : 0.f;
            }
            xs[ci*9 + kh*3 + 0] = v0;
            xs[ci*9 + kh*3 + 1] = v1;
            xs[ci*9 + kh*3 + 2] = v2;
        }
    }
    v2f xp[13];
    #pragma unroll
    for (int q = 0; q < 13; ++q)
        xp[q] = (v2f){xs[2*q], xs[2*q + 1]};
    const float x26 = xs[26];

    // scalar output-plane bases
    float* out_xf = out                      + b*3*HWp  + pixb;
    float* out_m  = out + 4*3*HWp            + b*6*HWp  + pixb;
    float* out_S  = out + (4*3+4*6)*HWp      + b*36*HWp + pixb;
    float* out_y  = out + (4*3+4*6+4*36)*HWp + b*3*HWp  + pixb;

    float pb[15];   // wave B only: [0..5]=m, [6..11]=s, [12..14]=xf

    if (wid == 0) {
        // ======== wave A: conv(angle ch) -> Givens R -> (bar1) -> S einsum + stores ========
        float pa[15];
        #pragma unroll
        for (int o = 0; o < 15; ++o) {
            const int base = (12 + o) * 27;
            v2f acc2 = (v2f){0.f, 0.f};
            #pragma unroll
            for (int q = 0; q < 13; ++q) {
                v2f wq;
                wq.x = Wt[base + 2*q];
                wq.y = Wt[base + 2*q + 1];
                acc2 = fma2(xp[q], wq, acc2);
            }
            const float r = be[12 + o] + acc2.x + acc2.y;
            pa[o] = fmaf(x26, Wt[base + 26], r);
        }

        // R as column-major row-pairs; trig folded into the loop (kills cs/ss arrays)
        v2f Rc[6][3];
        #pragma unroll
        for (int c = 0; c < 6; ++c)
            #pragma unroll
            for (int p = 0; p < 3; ++p)
                Rc[c][p] = (v2f){(2*p == c) ? 1.f : 0.f, (2*p + 1 == c) ? 1.f : 0.f};

        const int PI_[15] = {0,0,0,0,0,1,1,1,1,2,2,2,3,3,4};
        const int PJ_[15] = {1,2,3,4,5,2,3,4,5,3,4,5,4,5,5};
        #pragma unroll
        for (int k = 0; k < 15; ++k) {
            const int i = PI_[k], j = PJ_[k];
            const float e  = __expf(-pa[k]);
            const float sg = __builtin_amdgcn_rcpf(1.f + e);     // sigmoid
            const float c  = __builtin_amdgcn_cosf(sg);          // cos(2*pi*sg)
            const float sn = __builtin_amdgcn_sinf(sg);          // sin(2*pi*sg)
            const v2f c2 = (v2f){c, c};
            const v2f s2 = (v2f){sn, sn};
            #pragma unroll
            for (int p = 0; p < 3; ++p) {
                const v2f ri = Rc[i][p], rj = Rc[j][p];
                Rc[i][p] = fma2(c2, ri, s2 * rj);
                Rc[j][p] = fma2(c2, rj, -(s2 * ri));
            }
        }

        __syncthreads();    // bar1: d ready from wave B

        float dk[6];
        #pragma unroll
        for (int k = 0; k < 6; ++k)
            dk[k] = Dsh[k][lane];

        // S column-by-column: S[:,n] = sum_k (d[k]*R[n][k]) * R[:,k]
        #pragma unroll
        for (int n = 0; n < 6; ++n) {
            float t[6];
            #pragma unroll
            for (int k = 0; k < 6; ++k) {
                const float rnk = (n & 1) ? Rc[k][n >> 1].y : Rc[k][n >> 1].x;
                t[k] = dk[k] * rnk;
            }
            v2f col[3];
            #pragma unroll
            for (int p = 0; p < 3; ++p) {
                v2f acc = Rc[0][p] * (v2f){t[0], t[0]};
                #pragma unroll
                for (int k = 1; k < 6; ++k)
                    acc = fma2(Rc[k][p], (v2f){t[k], t[k]}, acc);
                col[p] = acc;
            }
            // stores: rows 0..5 of column n
            #pragma unroll
            for (int p = 0; p < 3; ++p) {
                out_S[((2*p    )*6 + n)*HWp + lane] = col[p].x;
                out_S[((2*p + 1)*6 + n)*HWp + lane] = col[p].y;
            }
            // publish rows 3..5 for wave B (syx / syy)
            Ssh[n*3 + 0][lane] = col[1].y;
            Ssh[n*3 + 1][lane] = col[2].x;
            Ssh[n*3 + 2][lane] = col[2].y;
        }

        __syncthreads();    // bar2: S rows published
        // wave A done
    } else {
        // ======== wave B: conv(m/s/xf ch) -> stores m,xf -> d -> (bars) -> f64 tail ========
        #pragma unroll
        for (int o = 0; o < 15; ++o) {
            const int ch   = (o < 12) ? o : (o + 15);
            const int base = ch * 27;
            v2f acc2 = (v2f){0.f, 0.f};
            #pragma unroll
            for (int q = 0; q < 13; ++q) {
                v2f wq;
                wq.x = Wt[base + 2*q];
                wq.y = Wt[base + 2*q + 1];
                acc2 = fma2(xp[q], wq, acc2);
            }
            const float r = be[ch] + acc2.x + acc2.y;
            pb[o] = fmaf(x26, Wt[base + 26], r);
        }

        #pragma unroll
        for (int c = 0; c < 6; ++c)
            out_m[c*HWp + lane] = pb[c];
        #pragma unroll
        for (int i = 0; i < 3; ++i)
            out_xf[i*HWp + lane] = pb[12 + i];

        // d = clip(s^2, 1e-6); publish for wave A
        #pragma unroll
        for (int k = 0; k < 6; ++k) {
            const float s = pb[6 + k];
            Dsh[k][lane] = fmaxf(s * s, 1e-6f);
        }

        __syncthreads();    // bar1
        __syncthreads();    // bar2: S rows 3..5 available

        // syx[r][c] = S[3+r][c], syy[r][c] = S[3+r][3+c]
        float syxf[3][3], syyf[3][3];
        #pragma unroll
        for (int c = 0; c < 3; ++c)
            #pragma unroll
            for (int r = 0; r < 3; ++r) {
                syxf[r][c] = Ssh[c*3 + r][lane];
                syyf[r][c] = Ssh[(3 + c)*3 + r][lane];
            }

        // Q = -S_yy^{-1} S_yx  (exact identity; f64 inverse of well-scaled block)
        const double a00 = (double)syyf[0][0], a01 = (double)syyf[0][1], a02 = (double)syyf[0][2];
        const double a10 = (double)syyf[1][0], a11 = (double)syyf[1][1], a12 = (double)syyf[1][2];
        const double a20 = (double)syyf[2][0], a21 = (double)syyf[2][1], a22 = (double)syyf[2][2];

        const double det = a00*(a11*a22 - a12*a21)
                         - a01*(a10*a22 - a12*a20)
                         + a02*(a10*a21 - a11*a20);
        const double idet = 1.0 / det;

        double inv[3][3];
        inv[0][0] =  (a11*a22 - a12*a21) * idet;
        inv[0][1] = -(a01*a22 - a02*a21) * idet;
        inv[0][2] =  (a01*a12 - a02*a11) * idet;
        inv[1][0] = -(a10*a22 - a12*a20) * idet;
        inv[1][1] =  (a00*a22 - a02*a20) * idet;
        inv[1][2] = -(a00*a12 - a02*a10) * idet;
        inv[2][0] =  (a10*a21 - a11*a20) * idet;
        inv[2][1] = -(a00*a21 - a01*a20) * idet;
        inv[2][2] =  (a00*a11 - a01*a10) * idet;

        double Qp[3][3];
        #pragma unroll
        for (int r = 0; r < 3; ++r)
            #pragma unroll
            for (int c = 0; c < 3; ++c) {
                double acc = 0.0;
                #pragma unroll
                for (int k = 0; k < 3; ++k)
                    acc = fma(inv[r][k], (double)syxf[k][c], acc);
                Qp[r][c] = acc;
            }

        // y = my - Qp (xf - mx)
        #pragma unroll
        for (int i = 0; i < 3; ++i) {
            double acc = (double)pb[3 + i];
            #pragma unroll
            for (int n = 0; n < 3; ++n)
                acc = fma(-Qp[i][n], (double)pb[12 + n] - (double)pb[n], acc);
            out_y[i*HWp + lane] = (float)acc;
        }
    }
}

extern "C" void kernel_launch(void* const* d_in, const int* in_sizes, int n_in,
                              void* d_out, int out_size, void* d_ws, size_t ws_size,
                              hipStream_t stream) {
    const float* x  = (const float*)d_in[0];
    const float* Wt = (const float*)d_in[1];
    const float* be = (const float*)d_in[2];
    float* out = (float*)d_out;

    dim3 grid(4096);   // 262144 pixels / 64 per block
    dim3 block(128);   // wave A (R/S) + wave B (conv/m/xf/d + f64 tail)
    hipLaunchKernelGGL(gp_encoder_kernel, grid, block, 0, stream, x, Wt, be, out);
}

// Round 8
// 21.894 us; speedup vs baseline: 1.0958x; 1.0958x over previous
//
#include <hip/hip_runtime.h>
#include <math.h>

#define HWp 65536   // 256*256

typedef float v2f __attribute__((ext_vector_type(2)));

__device__ __forceinline__ v2f fma2(v2f a, v2f b, v2f c) {
    return __builtin_elementwise_fma(a, b, c);
}
// streaming store: output is write-once, never re-read -> bypass L2 (nt)
__device__ __forceinline__ void stream_st(float* p, float v) {
    __builtin_nontemporal_store(v, p);
}

__global__ __launch_bounds__(128, 6)
void gp_encoder_kernel(const float* __restrict__ x,
                       const float* __restrict__ Wt,
                       const float* __restrict__ be,
                       float* __restrict__ out)
{
    // exchange buffers: [entry][lane], stride-1 per entry -> conflict-free
    __shared__ float Dsh[6][64];    // d6 from wave B
    __shared__ float Ssh[18][64];   // S rows 3..5 from wave A

    const int lane = threadIdx.x & 63;
    const int wid  = threadIdx.x >> 6;      // 0 = wave A (R + S), 1 = wave B (conv/m/xf/d + tail)

    // block-uniform coordinates (blocks are 64-aligned within one image row)
    const int blk  = blockIdx.x;
    const int b    = blk >> 10;
    const int pixb = (blk & 1023) << 6;
    const int h    = pixb >> 8;
    const int w0   = pixb & 255;

    const bool wlo_ok = !(w0 == 0   && lane == 0);
    const bool whi_ok = !(w0 == 192 && lane == 63);
    const int  idx_m1 = wlo_ok ? lane - 1 : lane;
    const int  idx_p1 = whi_ok ? lane + 1 : lane;

    // ---------------- 3x3x3 neighborhood ----------------
    float xs[27];
    const float* xb = x + b * 3 * HWp;
    #pragma unroll
    for (int ci = 0; ci < 3; ++ci) {
        #pragma unroll
        for (int kh = 0; kh < 3; ++kh) {
            const int hh = h + kh - 1;      // scalar
            float v0 = 0.f, v1 = 0.f, v2 = 0.f;
            if ((unsigned)hh < 256u) {      // uniform branch
                const float* rp = xb + ci * HWp + hh * 256 + w0;
                v0 = rp[idx_m1];
                v1 = rp[lane];
                v2 = rp[idx_p1];
                v0 = wlo_ok ? v0 : 0.f;
                v2 = whi_ok ? v2 : 0.f;
            }
            xs[ci*9 + kh*3 + 0] = v0;
            xs[ci*9 + kh*3 + 1] = v1;
            xs[ci*9 + kh*3 + 2] = v2;
        }
    }
    v2f xp[13];
    #pragma unroll
    for (int q = 0; q < 13; ++q)
        xp[q] = (v2f){xs[2*q], xs[2*q + 1]};
    const float x26 = xs[26];

    // scalar output-plane bases
    float* out_xf = out                      + b*3*HWp  + pixb;
    float* out_m  = out + 4*3*HWp            + b*6*HWp  + pixb;
    float* out_S  = out + (4*3+4*6)*HWp      + b*36*HWp + pixb;
    float* out_y  = out + (4*3+4*6+4*36)*HWp + b*3*HWp  + pixb;

    float pb[15];   // wave B only: [0..5]=m, [6..11]=s, [12..14]=xf

    if (wid == 0) {
        // ======== wave A: conv(angle ch) -> trig (ILP) -> Givens R -> (bar1) -> S ========
        float pa[15];
        #pragma unroll
        for (int o = 0; o < 15; ++o) {
            const int base = (12 + o) * 27;
            v2f acc2 = (v2f){0.f, 0.f};
            #pragma unroll
            for (int q = 0; q < 13; ++q) {
                v2f wq;
                wq.x = Wt[base + 2*q];
                wq.y = Wt[base + 2*q + 1];
                acc2 = fma2(xp[q], wq, acc2);
            }
            const float r = be[12 + o] + acc2.x + acc2.y;
            pa[o] = fmaf(x26, Wt[base + 26], r);
        }

        // 15 independent sigmoid/trig chains up front (overlapping TRANS latency)
        float cs[15], ss[15];
        #pragma unroll
        for (int k = 0; k < 15; ++k) {
            const float e  = __expf(-pa[k]);
            const float sg = __builtin_amdgcn_rcpf(1.f + e);   // sigmoid
            cs[k] = __builtin_amdgcn_cosf(sg);                 // cos(2*pi*sg)
            ss[k] = __builtin_amdgcn_sinf(sg);                 // sin(2*pi*sg)
        }

        // R as column-major row-pairs
        v2f Rc[6][3];
        #pragma unroll
        for (int c = 0; c < 6; ++c)
            #pragma unroll
            for (int p = 0; p < 3; ++p)
                Rc[c][p] = (v2f){(2*p == c) ? 1.f : 0.f, (2*p + 1 == c) ? 1.f : 0.f};

        const int PI_[15] = {0,0,0,0,0,1,1,1,1,2,2,2,3,3,4};
        const int PJ_[15] = {1,2,3,4,5,2,3,4,5,3,4,5,4,5,5};
        #pragma unroll
        for (int k = 0; k < 15; ++k) {
            const int i = PI_[k], j = PJ_[k];
            const v2f c2 = (v2f){cs[k], cs[k]};
            const v2f s2 = (v2f){ss[k], ss[k]};
            #pragma unroll
            for (int p = 0; p < 3; ++p) {
                const v2f ri = Rc[i][p], rj = Rc[j][p];
                Rc[i][p] = fma2(c2, ri, s2 * rj);
                Rc[j][p] = fma2(c2, rj, -(s2 * ri));
            }
        }

        __syncthreads();    // bar1: d ready from wave B

        float dk[6];
        #pragma unroll
        for (int k = 0; k < 6; ++k)
            dk[k] = Dsh[k][lane];

        // S column-by-column: S[:,n] = sum_k (d[k]*R[n][k]) * R[:,k]
        #pragma unroll
        for (int n = 0; n < 6; ++n) {
            float t[6];
            #pragma unroll
            for (int k = 0; k < 6; ++k) {
                const float rnk = (n & 1) ? Rc[k][n >> 1].y : Rc[k][n >> 1].x;
                t[k] = dk[k] * rnk;
            }
            v2f col[3];
            #pragma unroll
            for (int p = 0; p < 3; ++p) {
                v2f acc = Rc[0][p] * (v2f){t[0], t[0]};
                #pragma unroll
                for (int k = 1; k < 6; ++k)
                    acc = fma2(Rc[k][p], (v2f){t[k], t[k]}, acc);
                col[p] = acc;
            }
            #pragma unroll
            for (int p = 0; p < 3; ++p) {
                stream_st(&out_S[((2*p    )*6 + n)*HWp + lane], col[p].x);
                stream_st(&out_S[((2*p + 1)*6 + n)*HWp + lane], col[p].y);
            }
            // publish rows 3..5 for wave B (syx / syy)
            Ssh[n*3 + 0][lane] = col[1].y;
            Ssh[n*3 + 1][lane] = col[2].x;
            Ssh[n*3 + 2][lane] = col[2].y;
        }

        __syncthreads();    // bar2: S rows published
    } else {
        // ======== wave B: conv(m/s/xf ch) -> m,xf stores -> d -> (bars) -> f64 tail ========
        #pragma unroll
        for (int o = 0; o < 15; ++o) {
            const int ch   = (o < 12) ? o : (o + 15);
            const int base = ch * 27;
            v2f acc2 = (v2f){0.f, 0.f};
            #pragma unroll
            for (int q = 0; q < 13; ++q) {
                v2f wq;
                wq.x = Wt[base + 2*q];
                wq.y = Wt[base + 2*q + 1];
                acc2 = fma2(xp[q], wq, acc2);
            }
            const float r = be[ch] + acc2.x + acc2.y;
            pb[o] = fmaf(x26, Wt[base + 26], r);
        }

        #pragma unroll
        for (int c = 0; c < 6; ++c)
            stream_st(&out_m[c*HWp + lane], pb[c]);
        #pragma unroll
        for (int i = 0; i < 3; ++i)
            stream_st(&out_xf[i*HWp + lane], pb[12 + i]);

        // d = clip(s^2, 1e-6); publish for wave A
        #pragma unroll
        for (int k = 0; k < 6; ++k) {
            const float s = pb[6 + k];
            Dsh[k][lane] = fmaxf(s * s, 1e-6f);
        }

        __syncthreads();    // bar1
        __syncthreads();    // bar2: S rows 3..5 available

        float syxf[3][3], syyf[3][3];
        #pragma unroll
        for (int c = 0; c < 3; ++c)
            #pragma unroll
            for (int r = 0; r < 3; ++r) {
                syxf[r][c] = Ssh[c*3 + r][lane];
                syyf[r][c] = Ssh[(3 + c)*3 + r][lane];
            }

        // Q = -S_yy^{-1} S_yx  (exact identity; f64 inverse of well-scaled block)
        const double a00 = (double)syyf[0][0], a01 = (double)syyf[0][1], a02 = (double)syyf[0][2];
        const double a10 = (double)syyf[1][0], a11 = (double)syyf[1][1], a12 = (double)syyf[1][2];
        const double a20 = (double)syyf[2][0], a21 = (double)syyf[2][1], a22 = (double)syyf[2][2];

        const double det = a00*(a11*a22 - a12*a21)
                         - a01*(a10*a22 - a12*a20)
                         + a02*(a10*a21 - a11*a20);
        const double idet = 1.0 / det;

        double inv[3][3];
        inv[0][0] =  (a11*a22 - a12*a21) * idet;
        inv[0][1] = -(a01*a22 - a02*a21) * idet;
        inv[0][2] =  (a01*a12 - a02*a11) * idet;
        inv[1][0] = -(a10*a22 - a12*a20) * idet;
        inv[1][1] =  (a00*a22 - a02*a20) * idet;
        inv[1][2] = -(a00*a12 - a02*a10) * idet;
        inv[2][0] =  (a10*a21 - a11*a20) * idet;
        inv[2][1] = -(a00*a21 - a01*a20) * idet;
        inv[2][2] =  (a00*a11 - a01*a10) * idet;

        double Qp[3][3];
        #pragma unroll
        for (int r = 0; r < 3; ++r)
            #pragma unroll
            for (int c = 0; c < 3; ++c) {
                double acc = 0.0;
                #pragma unroll
                for (int k = 0; k < 3; ++k)
                    acc = fma(inv[r][k], (double)syxf[k][c], acc);
                Qp[r][c] = acc;
            }

        // y = my - Qp (xf - mx)
        #pragma unroll
        for (int i = 0; i < 3; ++i) {
            double acc = (double)pb[3 + i];
            #pragma unroll
            for (int n = 0; n < 3; ++n)
                acc = fma(-Qp[i][n], (double)pb[12 + n] - (double)pb[n], acc);
            stream_st(&out_y[i*HWp + lane], (float)acc);
        }
    }
}

extern "C" void kernel_launch(void* const* d_in, const int* in_sizes, int n_in,
                              void* d_out, int out_size, void* d_ws, size_t ws_size,
                              hipStream_t stream) {
    const float* x  = (const float*)d_in[0];
    const float* Wt = (const float*)d_in[1];
    const float* be = (const float*)d_in[2];
    float* out = (float*)d_out;

    dim3 grid(4096);   // 262144 pixels / 64 per block
    dim3 block(128);   // wave A (R/S) + wave B (conv/m/xf/d + f64 tail)
    hipLaunchKernelGGL(gp_encoder_kernel, grid, block, 0, stream, x, Wt, be, out);
}

// Round 9
// 21.716 us; speedup vs baseline: 1.1048x; 1.0082x over previous
//
#include <hip/hip_runtime.h>
#include <math.h>

#define HWp 65536   // 256*256

typedef float v2f __attribute__((ext_vector_type(2)));

__device__ __forceinline__ v2f fma2(v2f a, v2f b, v2f c) {
    return __builtin_elementwise_fma(a, b, c);   // v_pk_fma_f32
}
__device__ __forceinline__ void stream_st2(float* p, v2f v) {
    __builtin_nontemporal_store(v, (v2f*)p);     // 8B nt store, bypass L2
}
__device__ __forceinline__ float vget(v2f v, int px) { return px ? v.y : v.x; }

__global__ __launch_bounds__(128)
void gp_encoder_kernel(const float* __restrict__ x,
                       const float* __restrict__ Wt,
                       const float* __restrict__ be,
                       float* __restrict__ out)
{
    // exchange buffers (pixel-pair payloads): [entry][lane]
    __shared__ v2f Dsh[6][64];    // d from wave B
    __shared__ v2f Ssh[18][64];   // S rows 3..5 (x cols 0..5) from wave A

    const int lane = threadIdx.x & 63;
    const int wid  = threadIdx.x >> 6;     // 0 = wave A (R+S), 1 = wave B (conv/m/xf/d + f64 tail)

    // block-uniform tile coords: 128 contiguous pixels in one image row
    const int blk  = blockIdx.x;           // 2048 blocks
    const int b    = blk >> 9;             // 512 blocks per image
    const int pixb = (blk & 511) << 7;     // tile base pixel
    const int h    = pixb >> 8;
    const int w0   = pixb & 255;           // 0 or 128

    const int  c0     = 2 * lane;          // tile-local column of pixel0
    const bool wlo_ok = !(w0 == 0   && lane == 0);    // pixel0 left neighbor exists
    const bool whi_ok = !(w0 == 128 && lane == 63);   // pixel1 right neighbor exists
    const int  idx_l  = wlo_ok ? c0 - 1 : c0;         // safe (clamped) addresses
    const int  idx_r  = whi_ok ? c0 + 2 : c0;

    // ---------------- taps for BOTH pixels: 27 v2f ----------------
    // pixel0 cols (W-1,W,W+1) = {lv, mv.x, mv.y}; pixel1 = {mv.x, mv.y, rv}
    v2f tp[27];
    const float* xb = x + b * 3 * HWp;
    #pragma unroll
    for (int ci = 0; ci < 3; ++ci) {
        #pragma unroll
        for (int kh = 0; kh < 3; ++kh) {
            const int hh = h + kh - 1;     // scalar
            float lv = 0.f, rv = 0.f;
            v2f   mv = (v2f){0.f, 0.f};
            if ((unsigned)hh < 256u) {     // uniform branch
                const float* rp = xb + ci * HWp + hh * 256 + w0;
                mv = *reinterpret_cast<const v2f*>(rp + c0);
                lv = rp[idx_l];
                rv = rp[idx_r];
                lv = wlo_ok ? lv : 0.f;
                rv = whi_ok ? rv : 0.f;
            }
            tp[ci*9 + kh*3 + 0] = (v2f){lv, mv.x};
            tp[ci*9 + kh*3 + 1] = mv;
            tp[ci*9 + kh*3 + 2] = (v2f){mv.y, rv};
        }
    }

    // conv for one channel, both pixels; sequential t order (matches reference)
    auto conv_ch = [&](int ch) -> v2f {
        const float bb = be[ch];
        v2f acc = (v2f){bb, bb};
        const float* wp = Wt + ch * 27;
        #pragma unroll
        for (int t = 0; t < 27; ++t) {
            const float wt = wp[t];
            acc = fma2(tp[t], (v2f){wt, wt}, acc);
        }
        return acc;
    };

    // scalar output-plane bases (tile origin)
    float* out_xf = out                      + b*3*HWp  + pixb;
    float* out_m  = out + 4*3*HWp            + b*6*HWp  + pixb;
    float* out_S  = out + (4*3+4*6)*HWp      + b*36*HWp + pixb;
    float* out_y  = out + (4*3+4*6+4*36)*HWp + b*3*HWp  + pixb;

    if (wid == 0) {
        // ======== wave A: conv(angle) -> trig -> Givens -> (bar1) -> S + stores ========
        v2f pa[15];
        #pragma unroll
        for (int o = 0; o < 15; ++o)
            pa[o] = conv_ch(12 + o);

        // 15 angle pairs: sigmoid + sin/cos of 2*pi*sg (HW trig takes revolutions)
        v2f cs[15], ss[15];
        #pragma unroll
        for (int k = 0; k < 15; ++k) {
            const float e0 = __expf(-pa[k].x);
            const float e1 = __expf(-pa[k].y);
            const float g0 = __builtin_amdgcn_rcpf(1.f + e0);
            const float g1 = __builtin_amdgcn_rcpf(1.f + e1);
            cs[k] = (v2f){__builtin_amdgcn_cosf(g0), __builtin_amdgcn_cosf(g1)};
            ss[k] = (v2f){__builtin_amdgcn_sinf(g0), __builtin_amdgcn_sinf(g1)};
        }

        // R[6][6], each entry a pixel-pair
        v2f R[6][6];
        #pragma unroll
        for (int r = 0; r < 6; ++r)
            #pragma unroll
            for (int c = 0; c < 6; ++c)
                R[r][c] = (r == c) ? (v2f){1.f, 1.f} : (v2f){0.f, 0.f};

        const int PI_[15] = {0,0,0,0,0,1,1,1,1,2,2,2,3,3,4};
        const int PJ_[15] = {1,2,3,4,5,2,3,4,5,3,4,5,4,5,5};
        #pragma unroll
        for (int k = 0; k < 15; ++k) {
            const int i = PI_[k], j = PJ_[k];
            const v2f c2 = cs[k], s2 = ss[k];
            #pragma unroll
            for (int r = 0; r < 6; ++r) {
                const v2f ri = R[r][i], rj = R[r][j];
                R[r][i] = fma2(c2, ri, s2 * rj);
                R[r][j] = fma2(c2, rj, -(s2 * ri));
            }
        }

        __syncthreads();    // bar1: d ready from wave B

        v2f dk[6];
        #pragma unroll
        for (int k = 0; k < 6; ++k)
            dk[k] = Dsh[k][lane];

        // S = R diag(d) R^T, symmetric: compute r>=n, store both halves (nt dwordx2)
        #pragma unroll
        for (int n = 0; n < 6; ++n) {
            v2f t[6];
            #pragma unroll
            for (int k = 0; k < 6; ++k)
                t[k] = dk[k] * R[n][k];
            #pragma unroll
            for (int r = n; r < 6; ++r) {
                v2f acc = t[0] * R[r][0];
                #pragma unroll
                for (int k = 1; k < 6; ++k)
                    acc = fma2(t[k], R[r][k], acc);
                stream_st2(&out_S[(r*6 + n)*HWp + c0], acc);
                if (r != n)
                    stream_st2(&out_S[(n*6 + r)*HWp + c0], acc);
                // publish S rows 3..5 (all cols) for wave B
                if (r >= 3)           Ssh[n*3 + (r-3)][lane] = acc;  // S[r][n]
                if (n >= 3 && r != n) Ssh[r*3 + (n-3)][lane] = acc;  // S[n][r]
            }
        }

        __syncthreads();    // bar2
    } else {
        // ======== wave B: conv(m/s/xf) -> m,xf stores -> d -> (bars) -> f64 tail ========
        v2f pbm[6], pbs[6], pxf[3];
        #pragma unroll
        for (int o = 0; o < 6; ++o) pbm[o] = conv_ch(o);
        #pragma unroll
        for (int o = 0; o < 6; ++o) pbs[o] = conv_ch(6 + o);
        #pragma unroll
        for (int o = 0; o < 3; ++o) pxf[o] = conv_ch(27 + o);

        #pragma unroll
        for (int c = 0; c < 6; ++c)
            stream_st2(&out_m[c*HWp + c0], pbm[c]);
        #pragma unroll
        for (int i = 0; i < 3; ++i)
            stream_st2(&out_xf[i*HWp + c0], pxf[i]);

        // d = clip(s^2, 1e-6); publish for wave A
        #pragma unroll
        for (int k = 0; k < 6; ++k) {
            const v2f s = pbs[k];
            Dsh[k][lane] = __builtin_elementwise_max(s * s, (v2f){1e-6f, 1e-6f});
        }

        __syncthreads();    // bar1
        __syncthreads();    // bar2: S rows 3..5 available

        v2f syx2[3][3], syy2[3][3];
        #pragma unroll
        for (int c = 0; c < 3; ++c)
            #pragma unroll
            for (int r = 0; r < 3; ++r) {
                syx2[r][c] = Ssh[c*3 + r][lane];        // S[3+r][c]
                syy2[r][c] = Ssh[(3 + c)*3 + r][lane];  // S[3+r][3+c]
            }

        float yv[2][3];
        #pragma unroll
        for (int px = 0; px < 2; ++px) {
            // Q = -S_yy^{-1} S_yx (exact identity; f64 inverse of well-scaled block)
            const double a00 = (double)vget(syy2[0][0], px), a01 = (double)vget(syy2[0][1], px), a02 = (double)vget(syy2[0][2], px);
            const double a10 = (double)vget(syy2[1][0], px), a11 = (double)vget(syy2[1][1], px), a12 = (double)vget(syy2[1][2], px);
            const double a20 = (double)vget(syy2[2][0], px), a21 = (double)vget(syy2[2][1], px), a22 = (double)vget(syy2[2][2], px);

            const double det = a00*(a11*a22 - a12*a21)
                             - a01*(a10*a22 - a12*a20)
                             + a02*(a10*a21 - a11*a20);
            const double idet = 1.0 / det;

            double inv[3][3];
            inv[0][0] =  (a11*a22 - a12*a21) * idet;
            inv[0][1] = -(a01*a22 - a02*a21) * idet;
            inv[0][2] =  (a01*a12 - a02*a11) * idet;
            inv[1][0] = -(a10*a22 - a12*a20) * idet;
            inv[1][1] =  (a00*a22 - a02*a20) * idet;
            inv[1][2] = -(a00*a12 - a02*a10) * idet;
            inv[2][0] =  (a10*a21 - a11*a20) * idet;
            inv[2][1] = -(a00*a21 - a01*a20) * idet;
            inv[2][2] =  (a00*a11 - a01*a10) * idet;

            double Qp[3][3];
            #pragma unroll
            for (int r = 0; r < 3; ++r)
                #pragma unroll
                for (int c = 0; c < 3; ++c) {
                    double acc = 0.0;
                    #pragma unroll
                    for (int k = 0; k < 3; ++k)
                        acc = fma(inv[r][k], (double)vget(syx2[k][c], px), acc);
                    Qp[r][c] = acc;
                }

            // y = my - Qp (xf - mx)
            #pragma unroll
            for (int i = 0; i < 3; ++i) {
                double acc = (double)vget(pbm[3 + i], px);
                #pragma unroll
                for (int n = 0; n < 3; ++n)
                    acc = fma(-Qp[i][n], (double)vget(pxf[n], px) - (double)vget(pbm[n], px), acc);
                yv[px][i] = (float)acc;
            }
        }

        #pragma unroll
        for (int i = 0; i < 3; ++i)
            stream_st2(&out_y[i*HWp + c0], (v2f){yv[0][i], yv[1][i]});
    }
}

extern "C" void kernel_launch(void* const* d_in, const int* in_sizes, int n_in,
                              void* d_out, int out_size, void* d_ws, size_t ws_size,
                              hipStream_t stream) {
    const float* x  = (const float*)d_in[0];
    const float* Wt = (const float*)d_in[1];
    const float* be = (const float*)d_in[2];
    float* out = (float*)d_out;

    dim3 grid(2048);   // 262144 pixels / 128 per block
    dim3 block(128);   // 2 waves: A (R/S) + B (conv/m/xf/d + f64 tail); 2 px per lane
    hipLaunchKernelGGL(gp_encoder_kernel, grid, block, 0, stream, x, Wt, be, out);
}

// Round 10
// 21.062 us; speedup vs baseline: 1.1391x; 1.0310x over previous
//
#include <hip/hip_runtime.h>
#include <math.h>

#define HWp 65536   // 256*256

typedef float v2f __attribute__((ext_vector_type(2)));

__device__ __forceinline__ v2f fma2(v2f a, v2f b, v2f c) {
    return __builtin_elementwise_fma(a, b, c);   // v_pk_fma_f32
}
__device__ __forceinline__ void stream_st2(float* p, v2f v) {
    __builtin_nontemporal_store(v, (v2f*)p);     // 8B nt store, bypass L2
}
__device__ __forceinline__ float vget(v2f v, int px) { return px ? v.y : v.x; }

__global__ __launch_bounds__(128)
void gp_encoder_kernel(const float* __restrict__ x,
                       const float* __restrict__ Wt,
                       const float* __restrict__ be,
                       float* __restrict__ out)
{
    // one-way exchange B -> A (pixel-pair payloads): [entry][lane]
    __shared__ v2f Dsh[6][64];    // d
    __shared__ v2f Msh[6][64];    // m channels 0..5
    __shared__ v2f Xsh[3][64];    // xf

    const int lane = threadIdx.x & 63;
    const int wid  = threadIdx.x >> 6;     // 0 = wave A (R+S+tail), 1 = wave B (conv m/s/xf)

    // block-uniform tile coords: 128 contiguous pixels in one image row
    const int blk  = blockIdx.x;           // 2048 blocks
    const int b    = blk >> 9;             // 512 blocks per image
    const int pixb = (blk & 511) << 7;     // tile base pixel
    const int h    = pixb >> 8;
    const int w0   = pixb & 255;           // 0 or 128

    const int  c0     = 2 * lane;          // tile-local column of pixel0
    const bool wlo_ok = !(w0 == 0   && lane == 0);    // pixel0 left neighbor exists
    const bool whi_ok = !(w0 == 128 && lane == 63);   // pixel1 right neighbor exists
    const int  idx_l  = wlo_ok ? c0 - 1 : c0;
    const int  idx_r  = whi_ok ? c0 + 2 : c0;

    // ---------------- taps for BOTH pixels: 27 v2f ----------------
    v2f tp[27];
    const float* xb = x + b * 3 * HWp;
    #pragma unroll
    for (int ci = 0; ci < 3; ++ci) {
        #pragma unroll
        for (int kh = 0; kh < 3; ++kh) {
            const int hh = h + kh - 1;     // scalar
            float lv = 0.f, rv = 0.f;
            v2f   mv = (v2f){0.f, 0.f};
            if ((unsigned)hh < 256u) {     // uniform branch
                const float* rp = xb + ci * HWp + hh * 256 + w0;
                mv = *reinterpret_cast<const v2f*>(rp + c0);
                lv = rp[idx_l];
                rv = rp[idx_r];
                lv = wlo_ok ? lv : 0.f;
                rv = whi_ok ? rv : 0.f;
            }
            tp[ci*9 + kh*3 + 0] = (v2f){lv, mv.x};
            tp[ci*9 + kh*3 + 1] = mv;
            tp[ci*9 + kh*3 + 2] = (v2f){mv.y, rv};
        }
    }

    auto conv_ch = [&](int ch) -> v2f {
        const float bb = be[ch];
        v2f acc = (v2f){bb, bb};
        const float* wp = Wt + ch * 27;
        #pragma unroll
        for (int t = 0; t < 27; ++t) {
            const float wt = wp[t];
            acc = fma2(tp[t], (v2f){wt, wt}, acc);
        }
        return acc;
    };

    // scalar output-plane bases (tile origin)
    float* out_xf = out                      + b*3*HWp  + pixb;
    float* out_m  = out + 4*3*HWp            + b*6*HWp  + pixb;
    float* out_S  = out + (4*3+4*6)*HWp      + b*36*HWp + pixb;
    float* out_y  = out + (4*3+4*6+4*36)*HWp + b*3*HWp  + pixb;

    if (wid == 1) {
        // ======== wave B: conv(m/s/xf) -> store m,xf -> publish d,m,xf -> exit ========
        v2f pbm[6], pbs[6], pxf[3];
        #pragma unroll
        for (int o = 0; o < 6; ++o) pbm[o] = conv_ch(o);
        #pragma unroll
        for (int o = 0; o < 6; ++o) pbs[o] = conv_ch(6 + o);
        #pragma unroll
        for (int o = 0; o < 3; ++o) pxf[o] = conv_ch(27 + o);

        #pragma unroll
        for (int c = 0; c < 6; ++c) {
            stream_st2(&out_m[c*HWp + c0], pbm[c]);
            Msh[c][lane] = pbm[c];
        }
        #pragma unroll
        for (int i = 0; i < 3; ++i) {
            stream_st2(&out_xf[i*HWp + c0], pxf[i]);
            Xsh[i][lane] = pxf[i];
        }
        // d = clip(s^2, 1e-6)
        #pragma unroll
        for (int k = 0; k < 6; ++k) {
            const v2f s = pbs[k];
            Dsh[k][lane] = __builtin_elementwise_max(s * s, (v2f){1e-6f, 1e-6f});
        }

        __syncthreads();   // release A
        return;            // retire early, free SIMD slots
    }

    // ======== wave A: conv(angle) -> trig -> Givens -> (bar) -> S + f64 tail + y ========
    v2f pa[15];
    #pragma unroll
    for (int o = 0; o < 15; ++o)
        pa[o] = conv_ch(12 + o);

    // 15 angle pairs: sigmoid + sin/cos of 2*pi*sg (HW trig takes revolutions)
    v2f cs[15], ss[15];
    #pragma unroll
    for (int k = 0; k < 15; ++k) {
        const float e0 = __expf(-pa[k].x);
        const float e1 = __expf(-pa[k].y);
        const float g0 = __builtin_amdgcn_rcpf(1.f + e0);
        const float g1 = __builtin_amdgcn_rcpf(1.f + e1);
        cs[k] = (v2f){__builtin_amdgcn_cosf(g0), __builtin_amdgcn_cosf(g1)};
        ss[k] = (v2f){__builtin_amdgcn_sinf(g0), __builtin_amdgcn_sinf(g1)};
    }

    // R[6][6], each entry a pixel-pair
    v2f R[6][6];
    #pragma unroll
    for (int r = 0; r < 6; ++r)
        #pragma unroll
        for (int c = 0; c < 6; ++c)
            R[r][c] = (r == c) ? (v2f){1.f, 1.f} : (v2f){0.f, 0.f};

    const int PI_[15] = {0,0,0,0,0,1,1,1,1,2,2,2,3,3,4};
    const int PJ_[15] = {1,2,3,4,5,2,3,4,5,3,4,5,4,5,5};
    #pragma unroll
    for (int k = 0; k < 15; ++k) {
        const int i = PI_[k], j = PJ_[k];
        const v2f c2 = cs[k], s2 = ss[k];
        #pragma unroll
        for (int r = 0; r < 6; ++r) {
            const v2f ri = R[r][i], rj = R[r][j];
            R[r][i] = fma2(c2, ri, s2 * rj);
            R[r][j] = fma2(c2, rj, -(s2 * ri));
        }
    }

    __syncthreads();   // d, m, xf ready

    v2f dk[6], mm[6], xx[3];
    #pragma unroll
    for (int k = 0; k < 6; ++k) dk[k] = Dsh[k][lane];
    #pragma unroll
    for (int k = 0; k < 6; ++k) mm[k] = Msh[k][lane];
    #pragma unroll
    for (int k = 0; k < 3; ++k) xx[k] = Xsh[k][lane];

    // S = R diag(d) R^T, symmetric; keep syx/syy in registers for the tail
    v2f syx2[3][3], syy2[3][3];
    #pragma unroll
    for (int n = 0; n < 6; ++n) {
        v2f t[6];
        #pragma unroll
        for (int k = 0; k < 6; ++k)
            t[k] = dk[k] * R[n][k];
        #pragma unroll
        for (int r = n; r < 6; ++r) {
            v2f acc = t[0] * R[r][0];
            #pragma unroll
            for (int k = 1; k < 6; ++k)
                acc = fma2(t[k], R[r][k], acc);
            stream_st2(&out_S[(r*6 + n)*HWp + c0], acc);
            if (r != n)
                stream_st2(&out_S[(n*6 + r)*HWp + c0], acc);
            if (r >= 3 && n < 3)  syx2[r-3][n] = acc;              // S[3+i][j]
            if (r >= 3 && n >= 3) { syy2[r-3][n-3] = acc;
                                    if (r != n) syy2[n-3][r-3] = acc; }
        }
    }

    // f64 tail per pixel: Q = -S_yy^{-1} S_yx (exact identity), y = my - Qp(xf-mx)
    float yv[2][3];
    #pragma unroll
    for (int px = 0; px < 2; ++px) {
        const double a00 = (double)vget(syy2[0][0], px), a01 = (double)vget(syy2[0][1], px), a02 = (double)vget(syy2[0][2], px);
        const double a10 = (double)vget(syy2[1][0], px), a11 = (double)vget(syy2[1][1], px), a12 = (double)vget(syy2[1][2], px);
        const double a20 = (double)vget(syy2[2][0], px), a21 = (double)vget(syy2[2][1], px), a22 = (double)vget(syy2[2][2], px);

        const double det = a00*(a11*a22 - a12*a21)
                         - a01*(a10*a22 - a12*a20)
                         + a02*(a10*a21 - a11*a20);
        const double idet = 1.0 / det;

        double inv[3][3];
        inv[0][0] =  (a11*a22 - a12*a21) * idet;
        inv[0][1] = -(a01*a22 - a02*a21) * idet;
        inv[0][2] =  (a01*a12 - a02*a11) * idet;
        inv[1][0] = -(a10*a22 - a12*a20) * idet;
        inv[1][1] =  (a00*a22 - a02*a20) * idet;
        inv[1][2] = -(a00*a12 - a02*a10) * idet;
        inv[2][0] =  (a10*a21 - a11*a20) * idet;
        inv[2][1] = -(a00*a21 - a01*a20) * idet;
        inv[2][2] =  (a00*a11 - a01*a10) * idet;

        double Qp[3][3];
        #pragma unroll
        for (int r = 0; r < 3; ++r)
            #pragma unroll
            for (int c = 0; c < 3; ++c) {
                double acc = 0.0;
                #pragma unroll
                for (int k = 0; k < 3; ++k)
                    acc = fma(inv[r][k], (double)vget(syx2[k][c], px), acc);
                Qp[r][c] = acc;
            }

        #pragma unroll
        for (int i = 0; i < 3; ++i) {
            double acc = (double)vget(mm[3 + i], px);
            #pragma unroll
            for (int n = 0; n < 3; ++n)
                acc = fma(-Qp[i][n], (double)vget(xx[n], px) - (double)vget(mm[n], px), acc);
            yv[px][i] = (float)acc;
        }
    }

    #pragma unroll
    for (int i = 0; i < 3; ++i)
        stream_st2(&out_y[i*HWp + c0], (v2f){yv[0][i], yv[1][i]});
}

extern "C" void kernel_launch(void* const* d_in, const int* in_sizes, int n_in,
                              void* d_out, int out_size, void* d_ws, size_t ws_size,
                              hipStream_t stream) {
    const float* x  = (const float*)d_in[0];
    const float* Wt = (const float*)d_in[1];
    const float* be = (const float*)d_in[2];
    float* out = (float*)d_out;

    dim3 grid(2048);   // 262144 pixels / 128 per block
    dim3 block(128);   // wave A (R/S/tail) + wave B (conv m/s/xf, exits early)
    hipLaunchKernelGGL(gp_encoder_kernel, grid, block, 0, stream, x, Wt, be, out);
}

// Round 11
// 20.126 us; speedup vs baseline: 1.1921x; 1.0466x over previous
//
#include <hip/hip_runtime.h>
#include <math.h>

#define HWp 65536   // 256*256

typedef float v2f __attribute__((ext_vector_type(2)));
typedef float v4f __attribute__((ext_vector_type(4)));

__device__ __forceinline__ v2f fma2(v2f a, v2f b, v2f c) {
    return __builtin_elementwise_fma(a, b, c);   // v_pk_fma_f32
}
__device__ __forceinline__ void stream_st2(float* p, v2f v) {
    __builtin_nontemporal_store(v, (v2f*)p);     // 8B nt store
}
__device__ __forceinline__ void stream_st4(float* p, v4f v) {
    __builtin_nontemporal_store(v, (v4f*)p);     // 16B nt store
}
__device__ __forceinline__ float vget(v2f v, int px) { return px ? v.y : v.x; }

// tile row for S plane (i,j): unique entries enumerated col n=min, row r=max
__host__ __device__ constexpr int TRW(int p) {
    const int i = p / 6, j = p % 6;
    const int n = (i < j) ? i : j;
    const int r = (i < j) ? j : i;
    return 6*n - (n*(n-1))/2 + (r - n);
}

__global__ __launch_bounds__(256)
void gp_encoder_kernel(const float* __restrict__ x,
                       const float* __restrict__ Wt,
                       const float* __restrict__ be,
                       float* __restrict__ out)
{
    // B -> A exchange (pixel-pair payloads), indexed [entry][half*64+lane]
    __shared__ v2f Dsh[6][128];
    __shared__ v2f Msh[6][128];
    __shared__ v2f Xsh[3][128];
    // S store-transpose tile: 21 unique entries x 256 px (+4 pad, 16B-aligned rows)
    __shared__ float Stile[21][260];

    const int tid  = threadIdx.x;
    const int lane = tid & 63;
    const int wid  = tid >> 6;        // 0,1 = A halves; 2,3 = B halves
    const bool isA = wid < 2;
    const int  half = wid & 1;        // which 128-px half of the row

    // one block = one image row (256 px)
    const int blk  = blockIdx.x;      // 1024 blocks
    const int b    = blk >> 8;        // image
    const int h    = blk & 255;       // row
    const int pixb = h << 8;

    const int  ph = half << 7;        // 0 or 128
    const int  c0 = ph + 2 * lane;    // row-local column of pixel0
    const bool wlo_ok = (c0 != 0);
    const bool whi_ok = (c0 != 254);
    const int  idx_l  = wlo_ok ? c0 - 1 : c0;
    const int  idx_r  = whi_ok ? c0 + 2 : c0;
    const int  xi     = (half << 6) + lane;   // exchange index

    // ---------------- taps for BOTH pixels: 27 v2f ----------------
    v2f tp[27];
    #pragma unroll
    for (int ci = 0; ci < 3; ++ci) {
        #pragma unroll
        for (int kh = 0; kh < 3; ++kh) {
            const int hh = h + kh - 1;     // scalar
            float lv = 0.f, rv = 0.f;
            v2f   mv = (v2f){0.f, 0.f};
            if ((unsigned)hh < 256u) {     // uniform branch
                const float* rp = x + (b*3 + ci) * HWp + hh * 256;
                mv = *reinterpret_cast<const v2f*>(rp + c0);
                lv = rp[idx_l];
                rv = rp[idx_r];
                lv = wlo_ok ? lv : 0.f;
                rv = whi_ok ? rv : 0.f;
            }
            tp[ci*9 + kh*3 + 0] = (v2f){lv, mv.x};
            tp[ci*9 + kh*3 + 1] = mv;
            tp[ci*9 + kh*3 + 2] = (v2f){mv.y, rv};
        }
    }

    auto conv_ch = [&](int ch) -> v2f {
        const float bb = be[ch];
        v2f acc = (v2f){bb, bb};
        const float* wp = Wt + ch * 27;
        #pragma unroll
        for (int t = 0; t < 27; ++t) {
            const float wt = wp[t];
            acc = fma2(tp[t], (v2f){wt, wt}, acc);
        }
        return acc;
    };

    // scalar output-plane bases (row origin)
    float* out_xf = out                      + b*3*HWp  + pixb;
    float* out_m  = out + 4*3*HWp            + b*6*HWp  + pixb;
    float* out_S  = out + (4*3+4*6)*HWp      + b*36*HWp + pixb;
    float* out_y  = out + (4*3+4*6+4*36)*HWp + b*3*HWp  + pixb;

    if (!isA) {
        // ======== wave B: conv(m/s/xf) -> store m,xf -> publish d,m,xf ========
        v2f pbm[6], pbs[6], pxf[3];
        #pragma unroll
        for (int o = 0; o < 6; ++o) pbm[o] = conv_ch(o);
        #pragma unroll
        for (int o = 0; o < 6; ++o) pbs[o] = conv_ch(6 + o);
        #pragma unroll
        for (int o = 0; o < 3; ++o) pxf[o] = conv_ch(27 + o);

        #pragma unroll
        for (int c = 0; c < 6; ++c) {
            stream_st2(&out_m[c*HWp + c0], pbm[c]);
            Msh[c][xi] = pbm[c];
        }
        #pragma unroll
        for (int i = 0; i < 3; ++i) {
            stream_st2(&out_xf[i*HWp + c0], pxf[i]);
            Xsh[i][xi] = pxf[i];
        }
        #pragma unroll
        for (int k = 0; k < 6; ++k) {
            const v2f s = pbs[k];
            Dsh[k][xi] = __builtin_elementwise_max(s * s, (v2f){1e-6f, 1e-6f});
        }

        __syncthreads();   // bar1: release A
        __syncthreads();   // bar2: A's Stile writes done (B just passes through)
        return;
    }

    // ======== wave A: conv(angle) -> trig -> Givens -> S -> tile stores -> tail ========
    v2f pa[15];
    #pragma unroll
    for (int o = 0; o < 15; ++o)
        pa[o] = conv_ch(12 + o);

    // sigmoid + sin/cos of 2*pi*sg (HW trig takes revolutions)
    v2f cs[15], ss[15];
    #pragma unroll
    for (int k = 0; k < 15; ++k) {
        const float e0 = __expf(-pa[k].x);
        const float e1 = __expf(-pa[k].y);
        const float g0 = __builtin_amdgcn_rcpf(1.f + e0);
        const float g1 = __builtin_amdgcn_rcpf(1.f + e1);
        cs[k] = (v2f){__builtin_amdgcn_cosf(g0), __builtin_amdgcn_cosf(g1)};
        ss[k] = (v2f){__builtin_amdgcn_sinf(g0), __builtin_amdgcn_sinf(g1)};
    }

    v2f R[6][6];
    #pragma unroll
    for (int r = 0; r < 6; ++r)
        #pragma unroll
        for (int c = 0; c < 6; ++c)
            R[r][c] = (r == c) ? (v2f){1.f, 1.f} : (v2f){0.f, 0.f};

    const int PI_[15] = {0,0,0,0,0,1,1,1,1,2,2,2,3,3,4};
    const int PJ_[15] = {1,2,3,4,5,2,3,4,5,3,4,5,4,5,5};
    #pragma unroll
    for (int k = 0; k < 15; ++k) {
        const int i = PI_[k], j = PJ_[k];
        const v2f c2 = cs[k], s2 = ss[k];
        #pragma unroll
        for (int r = 0; r < 6; ++r) {
            const v2f ri = R[r][i], rj = R[r][j];
            R[r][i] = fma2(c2, ri, s2 * rj);
            R[r][j] = fma2(c2, rj, -(s2 * ri));
        }
    }

    __syncthreads();   // bar1: d, m, xf ready

    v2f dk[6];
    #pragma unroll
    for (int k = 0; k < 6; ++k) dk[k] = Dsh[k][xi];

    // S = R diag(d) R^T: 21 unique entries -> Stile; keep syx/syy for the tail
    v2f syx2[3][3], syy2[3][3];
    #pragma unroll
    for (int n = 0; n < 6; ++n) {
        v2f t[6];
        #pragma unroll
        for (int k = 0; k < 6; ++k)
            t[k] = dk[k] * R[n][k];
        #pragma unroll
        for (int r = n; r < 6; ++r) {
            v2f acc = t[0] * R[r][0];
            #pragma unroll
            for (int k = 1; k < 6; ++k)
                acc = fma2(t[k], R[r][k], acc);
            *reinterpret_cast<v2f*>(&Stile[TRW(r*6 + n)][c0]) = acc;
            if (r >= 3 && n < 3)  syx2[r-3][n] = acc;
            if (r >= 3 && n >= 3) { syy2[r-3][n-3] = acc;
                                    if (r != n) syy2[n-3][r-3] = acc; }
        }
    }

    __syncthreads();   // bar2: both A halves done writing Stile

    // cooperative plane stores: 36 planes x 1KB full-row nt dwordx4 (18 per half)
    #define STP(p) { v4f v = *reinterpret_cast<const v4f*>(&Stile[TRW(p)][4*lane]); \
                     stream_st4(&out_S[(p)*HWp + 4*lane], v); }
    if (half == 0) {
        STP(0)  STP(2)  STP(4)  STP(6)  STP(8)  STP(10)
        STP(12) STP(14) STP(16) STP(18) STP(20) STP(22)
        STP(24) STP(26) STP(28) STP(30) STP(32) STP(34)
    } else {
        STP(1)  STP(3)  STP(5)  STP(7)  STP(9)  STP(11)
        STP(13) STP(15) STP(17) STP(19) STP(21) STP(23)
        STP(25) STP(27) STP(29) STP(31) STP(33) STP(35)
    }
    #undef STP

    // f64 tail: Q = -S_yy^{-1} S_yx (exact identity), y = my - Qp(xf - mx)
    v2f mm[6], xx[3];
    #pragma unroll
    for (int k = 0; k < 6; ++k) mm[k] = Msh[k][xi];
    #pragma unroll
    for (int k = 0; k < 3; ++k) xx[k] = Xsh[k][xi];

    float yv[2][3];
    #pragma unroll
    for (int px = 0; px < 2; ++px) {
        const double a00 = (double)vget(syy2[0][0], px), a01 = (double)vget(syy2[0][1], px), a02 = (double)vget(syy2[0][2], px);
        const double a10 = (double)vget(syy2[1][0], px), a11 = (double)vget(syy2[1][1], px), a12 = (double)vget(syy2[1][2], px);
        const double a20 = (double)vget(syy2[2][0], px), a21 = (double)vget(syy2[2][1], px), a22 = (double)vget(syy2[2][2], px);

        const double det = a00*(a11*a22 - a12*a21)
                         - a01*(a10*a22 - a12*a20)
                         + a02*(a10*a21 - a11*a20);
        const double idet = 1.0 / det;

        double inv[3][3];
        inv[0][0] =  (a11*a22 - a12*a21) * idet;
        inv[0][1] = -(a01*a22 - a02*a21) * idet;
        inv[0][2] =  (a01*a12 - a02*a11) * idet;
        inv[1][0] = -(a10*a22 - a12*a20) * idet;
        inv[1][1] =  (a00*a22 - a02*a20) * idet;
        inv[1][2] = -(a00*a12 - a02*a10) * idet;
        inv[2][0] =  (a10*a21 - a11*a20) * idet;
        inv[2][1] = -(a00*a21 - a01*a20) * idet;
        inv[2][2] =  (a00*a11 - a01*a10) * idet;

        double Qp[3][3];
        #pragma unroll
        for (int r = 0; r < 3; ++r)
            #pragma unroll
            for (int c = 0; c < 3; ++c) {
                double acc = 0.0;
                #pragma unroll
                for (int k = 0; k < 3; ++k)
                    acc = fma(inv[r][k], (double)vget(syx2[k][c], px), acc);
                Qp[r][c] = acc;
            }

        #pragma unroll
        for (int i = 0; i < 3; ++i) {
            double acc = (double)vget(mm[3 + i], px);
            #pragma unroll
            for (int n = 0; n < 3; ++n)
                acc = fma(-Qp[i][n], (double)vget(xx[n], px) - (double)vget(mm[n], px), acc);
            yv[px][i] = (float)acc;
        }
    }

    #pragma unroll
    for (int i = 0; i < 3; ++i)
        stream_st2(&out_y[i*HWp + c0], (v2f){yv[0][i], yv[1][i]});
}

extern "C" void kernel_launch(void* const* d_in, const int* in_sizes, int n_in,
                              void* d_out, int out_size, void* d_ws, size_t ws_size,
                              hipStream_t stream) {
    const float* x  = (const float*)d_in[0];
    const float* Wt = (const float*)d_in[1];
    const float* be = (const float*)d_in[2];
    float* out = (float*)d_out;

    dim3 grid(1024);   // 4 images x 256 rows; one row per block
    dim3 block(256);   // A0,A1 (pipeline) + B0,B1 (conv m/s/xf)
    hipLaunchKernelGGL(gp_encoder_kernel, grid, block, 0, stream, x, Wt, be, out);
}